// Round 2
// baseline (429.045 us; speedup 1.0000x reference)
//
#include <hip/hip_runtime.h>
#include <math.h>

#define NN 512
#define HD 64
#define EPSV 1e-5f

// ---------------- generic tiled gemm: C = act(A@B + bias) ----------------
#define TS 16
__global__ void gemm_kernel(const float* __restrict__ A, const float* __restrict__ B,
                            const float* __restrict__ bias, float* __restrict__ C,
                            int M, int K, int Nn, int act) {
  __shared__ float As[TS][TS + 1];
  __shared__ float Bs[TS][TS + 1];
  int tx = threadIdx.x, ty = threadIdx.y;
  int row = blockIdx.y * TS + ty;
  int col = blockIdx.x * TS + tx;
  float acc = 0.f;
  for (int k0 = 0; k0 < K; k0 += TS) {
    As[ty][tx] = (row < M && (k0 + tx) < K) ? A[row * K + k0 + tx] : 0.f;
    Bs[ty][tx] = ((k0 + ty) < K && col < Nn) ? B[(k0 + ty) * Nn + col] : 0.f;
    __syncthreads();
#pragma unroll
    for (int kk = 0; kk < TS; ++kk) acc += As[ty][kk] * Bs[kk][tx];
    __syncthreads();
  }
  if (row < M && col < Nn) {
    float v = acc + (bias ? bias[col] : 0.f);
    if (act) v = fmaxf(v, 0.f);
    C[row * Nn + col] = v;
  }
}

// ---------------- w[i] = dot(A[i,:], v)  (one wave per row) ----------------
__global__ void rowdot_kernel(const float* __restrict__ A, const float* __restrict__ v,
                              float* __restrict__ out, int K) {
  int i = blockIdx.x;
  int lane = threadIdx.x;
  float s = 0.f;
  for (int k = lane; k < K; k += 64) s += A[i * K + k] * v[k];
#pragma unroll
  for (int off = 32; off > 0; off >>= 1) s += __shfl_down(s, off, 64);
  if (lane == 0) out[i] = s;
}

// ---------------- H1: masked row softmax of w[j] over adj, then @Wh1 ------
__global__ void h1_kernel(const float* __restrict__ Wh1, const float* __restrict__ wsc,
                          const int* __restrict__ adj, float* __restrict__ H1) {
  __shared__ float el[NN];
  __shared__ float red[256];
  int i = blockIdx.x, tid = threadIdx.x;
  float m = -INFINITY;
  for (int j = tid; j < NN; j += 256) {
    float val = (adj[i * NN + j] != 0) ? wsc[j] : -INFINITY;
    el[j] = val;
    m = fmaxf(m, val);
  }
  red[tid] = m; __syncthreads();
  for (int s = 128; s > 0; s >>= 1) { if (tid < s) red[tid] = fmaxf(red[tid], red[tid + s]); __syncthreads(); }
  float mw = red[0];
  __syncthreads();
  float sum = 0.f;
  for (int j = tid; j < NN; j += 256) {
    float val = el[j];
    float e = (val == -INFINITY) ? 0.f : expf(val - mw);
    el[j] = e;
    sum += e;
  }
  red[tid] = sum; __syncthreads();
  for (int s = 128; s > 0; s >>= 1) { if (tid < s) red[tid] += red[tid + s]; __syncthreads(); }
  float inv = 1.f / red[0];
  __syncthreads();
  float acc = 0.f;
#pragma unroll 4
  for (int j = 0; j < NN; ++j) acc += el[j] * Wh1[j * 256 + tid];
  H1[i * 256 + tid] = acc * inv;
}

// ---------------- wc[k] = sum_h ce_w2[k,h]*(a_c0[h]+a_c1[h]) ----------------
__global__ void wc_kernel(const float* __restrict__ ce_w2, const float* __restrict__ a_c0,
                          const float* __restrict__ a_c1, float* __restrict__ wc) {
  __shared__ float acl[HD];
  int tid = threadIdx.x;
  if (tid < HD) acl[tid] = a_c0[tid] + a_c1[tid];
  __syncthreads();
  float s = 0.f;
#pragma unroll 8
  for (int h = 0; h < HD; ++h) s += ce_w2[tid * HD + h] * acl[h];
  wc[tid] = s;
}

// ---------------- pair kernel: per-block online softmax partials ----------
__global__ __launch_bounds__(256) void pair_kernel(
    const float* __restrict__ P, const float* __restrict__ Q,
    const float* __restrict__ b1, const float* __restrict__ wc,
    float* __restrict__ mpart, float* __restrict__ dpart, float* __restrict__ rpart) {
  __shared__ float Pl[16 * 257];
  __shared__ float Ql[16 * 257];
  __shared__ float bw[256];
  __shared__ float wcl[256];
  __shared__ float el[256];
  __shared__ float red[256];
  int tid = threadIdx.x;
  int i0 = blockIdx.y * 16, j0 = blockIdx.x * 16;
  for (int e = tid; e < 4096; e += 256) {
    int r = e >> 8, c = e & 255;
    Pl[r * 257 + c] = P[(i0 + r) * 256 + c];
    Ql[r * 257 + c] = Q[(j0 + r) * 256 + c];
  }
  bw[tid] = b1[tid];
  wcl[tid] = wc[tid];
  __syncthreads();
  int ti = tid >> 4, tj = tid & 15;
  const float* pr = &Pl[ti * 257];
  const float* qr = &Ql[tj * 257];
  float acc = 0.f;
#pragma unroll 4
  for (int k = 0; k < 256; ++k) {
    float v = pr[k] + qr[k] + bw[k];
    acc += fmaxf(v, 0.f) * wcl[k];
  }
  if (i0 + ti == j0 + tj) acc = -INFINITY;  // diagonal mask
  red[tid] = acc; __syncthreads();
  for (int s = 128; s > 0; s >>= 1) { if (tid < s) red[tid] = fmaxf(red[tid], red[tid + s]); __syncthreads(); }
  float mb = red[0];   // finite: at most 16 of 256 entries are -inf
  __syncthreads();
  float e = expf(acc - mb);  // -inf -> 0
  el[tid] = e;
  red[tid] = e; __syncthreads();
  for (int s = 128; s > 0; s >>= 1) { if (tid < s) red[tid] += red[tid + s]; __syncthreads(); }
  float db = red[0];
  // r accumulation: thread owns feature k = tid
  float bk = bw[tid];
  float rk = 0.f;
  for (int p = 0; p < 256; ++p) {
    float ep = el[p];
    int ip = p >> 4, jp = p & 15;
    float v = Pl[ip * 257 + tid] + Ql[jp * 257 + tid] + bk;
    rk += ep * fmaxf(v, 0.f);
  }
  int b = blockIdx.y * 32 + blockIdx.x;
  rpart[b * 256 + tid] = rk;
  if (tid == 0) { mpart[b] = mb; dpart[b] = db; }
}

__global__ void maxreduce_kernel(const float* __restrict__ in, int n, float* __restrict__ out) {
  __shared__ float red[256];
  int tid = threadIdx.x;
  float m = -INFINITY;
  for (int idx = tid; idx < n; idx += 256) m = fmaxf(m, in[idx]);
  red[tid] = m; __syncthreads();
  for (int s = 128; s > 0; s >>= 1) { if (tid < s) red[tid] = fmaxf(red[tid], red[tid + s]); __syncthreads(); }
  if (tid == 0) out[0] = red[0];
}

// blocks 0..255 reduce rvec[k]; block 256 reduces D
__global__ void combine_kernel(const float* __restrict__ mpart, const float* __restrict__ dpart,
                               const float* __restrict__ rpart, const float* __restrict__ Mptr,
                               float* __restrict__ rvec, float* __restrict__ Dval) {
  __shared__ float red[256];
  int tid = threadIdx.x;
  float M = Mptr[0];
  int k = blockIdx.x;
  float s = 0.f;
  if (k < 256) {
    for (int b = tid; b < 1024; b += 256) s += expf(mpart[b] - M) * rpart[b * 256 + k];
  } else {
    for (int b = tid; b < 1024; b += 256) s += expf(mpart[b] - M) * dpart[b];
  }
  red[tid] = s; __syncthreads();
  for (int t = 128; t > 0; t >>= 1) { if (tid < t) red[tid] += red[tid + t]; __syncthreads(); }
  if (tid == 0) { if (k < 256) rvec[k] = red[0]; else Dval[0] = red[0]; }
}

__global__ void h2row_kernel(const float* __restrict__ rvec, const float* __restrict__ Dval,
                             const float* __restrict__ ce_w2, const float* __restrict__ ce_b2,
                             float* __restrict__ H2row) {
  int h = threadIdx.x;  // 64
  float invD = 1.f / Dval[0];
  float s = 0.f;
  for (int k = 0; k < 256; ++k) s += rvec[k] * ce_w2[k * HD + h];
  H2row[h] = s * invD + ce_b2[h];
}

// ---------------- concat [V, prev_hidden] ----------------
__global__ void catvp_kernel(const float* __restrict__ V, const float* __restrict__ ph,
                             float* __restrict__ out) {
  int idx = blockIdx.x * 256 + threadIdx.x;  // < 512*512
  int i = idx >> 9, c = idx & 511;
  out[idx] = (c < 256) ? V[i * 256 + c] : ph[i * 256 + (c - 256)];
}

// ---------------- H3: prefix mean of tf rows ----------------
// Reference broadcasts ts (N,1) -> (N,N): every unmasked entry in row i is
// ts[i], so the causal row softmax is UNIFORM over j<=i. H3[i] = mean(tf[0..i]).
// a_t0 / a_t1 are dead inputs.
__global__ void h3_kernel(const float* __restrict__ tf, float* __restrict__ H3) {
  int h = threadIdx.x;  // 64
  float acc = 0.f;
  for (int i = 0; i < NN; ++i) {
    acc += tf[i * HD + h];
    H3[i * HD + h] = acc / (float)(i + 1);
  }
}

// ---------------- first two neighbors per row ----------------
__global__ void nbr_kernel(const int* __restrict__ adj, int* __restrict__ nb) {
  int i = blockIdx.x;
  int lane = threadIdx.x;  // 64
  int n0 = -1, n1 = -1, cnt = 0;
  for (int c = 0; c < 8; ++c) {
    int j = c * 64 + lane;
    unsigned long long m = __ballot(adj[i * NN + j] != 0);
    cnt += (int)__popcll(m);
    if (n0 < 0 && m) { n0 = c * 64 + __builtin_ctzll(m); m &= (m - 1); }
    if (n1 < 0 && m) { n1 = c * 64 + __builtin_ctzll(m); }
  }
  if (lane == 0) {
    nb[i * 3] = n0;
    nb[i * 3 + 1] = n1;
    nb[i * 3 + 2] = (cnt >= 2) ? 1 : 0;
  }
}

// ---------------- build ci = [V, V[nb0], V[nb1]] ----------------
__global__ void ci_kernel(const float* __restrict__ V, const int* __restrict__ nb,
                          float* __restrict__ ci) {
  int idx = blockIdx.x * 256 + threadIdx.x;  // < 512*768
  int i = idx / 768;
  int c = idx - i * 768;
  float v;
  if (c < 256) {
    v = V[i * 256 + c];
  } else {
    int valid = nb[i * 3 + 2];
    if (!valid) v = 0.f;
    else {
      int src = (c < 512) ? nb[i * 3] : nb[i * 3 + 1];
      int cc = (c < 512) ? (c - 256) : (c - 512);
      v = V[src * 256 + cc];
    }
  }
  ci[idx] = v;
}

__global__ void colsum_kernel(const float* __restrict__ cf4, float* __restrict__ h4vec) {
  int h = threadIdx.x;  // 64
  float s = 0.f;
  for (int i = 0; i < NN; ++i) s += cf4[i * HD + h];
  h4vec[h] = s;
}

// ---------------- build Hc = [H1 | H2row | H3 | H4col] ----------------
__global__ void hc_build_kernel(const float* __restrict__ H1, const float* __restrict__ H2row,
                                const float* __restrict__ H3, const float* __restrict__ h4vec,
                                float* __restrict__ Hc) {
  int idx = blockIdx.x * 256 + threadIdx.x;
  if (idx >= NN * 385) return;
  int i = idx / 385;
  int c = idx - i * 385;
  float v;
  if (c < 256) v = H1[i * 256 + c];
  else if (c < 320) v = H2row[c - 256];
  else if (c < 384) v = H3[i * 64 + (c - 320)];
  else v = (i < 64) ? h4vec[i] : 0.f;
  Hc[idx] = v;
}

// ---------------- layernorm + elu ----------------
__global__ void ln_elu_kernel(const float* __restrict__ X, const float* __restrict__ g,
                              const float* __restrict__ b, float* __restrict__ out) {
  __shared__ float red[256];
  int i = blockIdx.x, tid = threadIdx.x;
  float x = X[i * 256 + tid];
  red[tid] = x; __syncthreads();
  for (int s = 128; s > 0; s >>= 1) { if (tid < s) red[tid] += red[tid + s]; __syncthreads(); }
  float mu = red[0] * (1.f / 256.f);
  __syncthreads();
  float d = x - mu;
  red[tid] = d * d; __syncthreads();
  for (int s = 128; s > 0; s >>= 1) { if (tid < s) red[tid] += red[tid + s]; __syncthreads(); }
  float var = red[0] * (1.f / 256.f);
  float y = d / sqrtf(var + EPSV) * g[tid] + b[tid];
  out[i * 256 + tid] = (y > 0.f) ? y : (expf(y) - 1.f);
}

extern "C" void kernel_launch(void* const* d_in, const int* in_sizes, int n_in,
                              void* d_out, int out_size, void* d_ws, size_t ws_size,
                              hipStream_t stream) {
  const float* V      = (const float*)d_in[0];
  const int*   adj    = (const int*)  d_in[1];
  const float* ph     = (const float*)d_in[2];
  const float* W1     = (const float*)d_in[3];
  // d_in[4] = a_std0: cancels in row softmax of s1 — unused
  const float* a_std1 = (const float*)d_in[5];
  const float* ce_w1  = (const float*)d_in[6];
  const float* ce_b1  = (const float*)d_in[7];
  const float* ce_w2  = (const float*)d_in[8];
  const float* ce_b2  = (const float*)d_in[9];
  const float* a_c0   = (const float*)d_in[10];
  const float* a_c1   = (const float*)d_in[11];
  const float* te_w1  = (const float*)d_in[12];
  const float* te_b1  = (const float*)d_in[13];
  const float* te_w2  = (const float*)d_in[14];
  const float* te_b2  = (const float*)d_in[15];
  // d_in[16], d_in[17] = a_t0, a_t1: dead (uniform causal softmax) — unused
  const float* co_w1  = (const float*)d_in[18];
  const float* co_b1  = (const float*)d_in[19];
  const float* co_w2  = (const float*)d_in[20];
  const float* co_b2  = (const float*)d_in[21];
  // d_in[22], d_in[23] = a_co0, a_co1: softmax over size-1 axis == 1 — unused
  const float* W2     = (const float*)d_in[24];
  const float* Wo     = (const float*)d_in[25];
  const float* bo     = (const float*)d_in[26];
  const float* ln_g   = (const float*)d_in[27];
  const float* ln_b   = (const float*)d_in[28];
  float* out = (float*)d_out;

  float* ws = (float*)d_ws;
  size_t off = 0;
  auto alloc = [&](size_t n) { float* p = ws + off; off += n; return p; };

  // region A (reused three times across the sequential dependency chain)
  float* regA = alloc(512 * 768);
  float* Wh1 = regA;               // phase 1
  float* Pb  = regA + 131072;
  float* Qb  = regA + 262144;
  float* ci  = regA;               // phase 2 (after pair stage consumed P/Q/Wh1)
  float* T1  = regA;               // phase 3 (after ci consumed)
  float* T2  = regA + 131072;
  float* wsc   = alloc(512);
  float* regB  = alloc(1024 * 256);  // rpart, then catvp
  float* rpart = regB;
  float* catvp = regB;
  float* wc    = alloc(256);
  float* mpart = alloc(1024);
  float* dpart = alloc(1024);
  float* Mcs   = alloc(1);
  float* rvec  = alloc(256);
  float* Dval  = alloc(1);
  float* H2row = alloc(64);
  float* tfh   = alloc(512 * 256);  // then cf4h
  float* cf4h  = tfh;
  float* tf    = alloc(512 * 64);
  float* H3    = alloc(512 * 64);
  int*   nb    = (int*)alloc(512 * 3);
  float* cf4   = alloc(512 * 64);
  float* h4vec = alloc(64);
  float* H1    = alloc(512 * 256);
  float* Hc    = alloc(512 * 385);
  (void)ws_size; (void)in_sizes; (void)n_in; (void)out_size;

  dim3 tb(16, 16);

  // --- H1 branch ---
  gemm_kernel<<<dim3(16, 32), tb, 0, stream>>>(V, W1, nullptr, Wh1, 512, 256, 256, 0);
  rowdot_kernel<<<512, 64, 0, stream>>>(Wh1, a_std1, wsc, 256);
  h1_kernel<<<512, 256, 0, stream>>>(Wh1, wsc, adj, H1);

  // --- H2 branch (pair MLP, algebraically reduced) ---
  gemm_kernel<<<dim3(16, 32), tb, 0, stream>>>(V, ce_w1, nullptr, Pb, 512, 256, 256, 0);
  gemm_kernel<<<dim3(16, 32), tb, 0, stream>>>(V, ce_w1 + 256 * 256, nullptr, Qb, 512, 256, 256, 0);
  wc_kernel<<<1, 256, 0, stream>>>(ce_w2, a_c0, a_c1, wc);
  pair_kernel<<<dim3(32, 32), 256, 0, stream>>>(Pb, Qb, ce_b1, wc, mpart, dpart, rpart);
  maxreduce_kernel<<<1, 256, 0, stream>>>(mpart, 1024, Mcs);
  combine_kernel<<<257, 256, 0, stream>>>(mpart, dpart, rpart, Mcs, rvec, Dval);
  h2row_kernel<<<1, 64, 0, stream>>>(rvec, Dval, ce_w2, ce_b2, H2row);

  // --- H3 branch ---
  catvp_kernel<<<1024, 256, 0, stream>>>(V, ph, catvp);
  gemm_kernel<<<dim3(16, 32), tb, 0, stream>>>(catvp, te_w1, te_b1, tfh, 512, 512, 256, 1);
  gemm_kernel<<<dim3(4, 32), tb, 0, stream>>>(tfh, te_w2, te_b2, tf, 512, 256, 64, 0);
  h3_kernel<<<1, 64, 0, stream>>>(tf, H3);

  // --- H4 branch ---
  nbr_kernel<<<512, 64, 0, stream>>>(adj, nb);
  ci_kernel<<<1536, 256, 0, stream>>>(V, nb, ci);
  gemm_kernel<<<dim3(16, 32), tb, 0, stream>>>(ci, co_w1, co_b1, cf4h, 512, 768, 256, 1);
  gemm_kernel<<<dim3(4, 32), tb, 0, stream>>>(cf4h, co_w2, co_b2, cf4, 512, 256, 64, 0);
  colsum_kernel<<<1, 64, 0, stream>>>(cf4, h4vec);

  // --- combine + output head ---
  hc_build_kernel<<<770, 256, 0, stream>>>(H1, H2row, H3, h4vec, Hc);
  gemm_kernel<<<dim3(16, 32), tb, 0, stream>>>(Hc, W2, nullptr, T1, 512, 385, 256, 0);
  gemm_kernel<<<dim3(16, 32), tb, 0, stream>>>(T1, Wo, bo, T2, 512, 256, 256, 0);
  ln_elu_kernel<<<512, 256, 0, stream>>>(T2, ln_g, ln_b, out);
}

// Round 3
// 402.725 us; speedup vs baseline: 1.0654x; 1.0654x over previous
//
#include <hip/hip_runtime.h>
#include <math.h>

#define NN 512
#define HD 64
#define EPSV 1e-5f

// ================= 64x64-tile GEMM, 256 threads, 4x4 per thread ==========
// MODE 0: plain A (M x K)
// MODE 1: A = concat[A (K1) | A2 (K-K1)] along columns
// MODE 2: A = gather3: cols 0-255 from A[row], 256-511 from A[nb0], 512-767 from A[nb1] (0 if !valid)
// MODE 3: A = virtual Hc: cols 0-255 A=H1[row], 256-319 A2=H2row (bcast), 320-383 A3=H3[row], 384 A4=h4col
template <int MODE>
__device__ __forceinline__ void gemm_body(
    const float* __restrict__ A, const float* __restrict__ A2,
    const float* __restrict__ A3, const float* __restrict__ A4,
    const int* __restrict__ nb,
    const float* __restrict__ B, const float* __restrict__ bias,
    float* __restrict__ C, int M, int K, int Nn, int act, int K1,
    int bx, int by) {
  __shared__ float As[64][68];
  __shared__ float Bs[64][68];
  int tx = threadIdx.x, ty = threadIdx.y;
  int t = ty * 16 + tx;
  int rowbase = by * 64, colbase = bx * 64;
  float acc[4][4];
#pragma unroll
  for (int i = 0; i < 4; ++i)
#pragma unroll
    for (int j = 0; j < 4; ++j) acc[i][j] = 0.f;

  for (int k0 = 0; k0 < K; k0 += 64) {
    // ---- load A tile (64 rows x 64 k) as float4 per thread x4 ----
#pragma unroll
    for (int j = 0; j < 4; ++j) {
      int idx = t + j * 256;
      int r = idx >> 4;
      int c0 = (idx & 15) * 4;
      int grow = rowbase + r;
      int gk = k0 + c0;
      float4 v = make_float4(0.f, 0.f, 0.f, 0.f);
      if (MODE == 0) {
        if (gk + 3 < K) {
          v = *(const float4*)&A[(size_t)grow * K + gk];
        } else {
          float tmp[4] = {0.f, 0.f, 0.f, 0.f};
#pragma unroll
          for (int e = 0; e < 4; ++e)
            if (gk + e < K) tmp[e] = A[(size_t)grow * K + gk + e];
          v = make_float4(tmp[0], tmp[1], tmp[2], tmp[3]);
        }
      } else if (MODE == 1) {
        if (gk < K1) v = *(const float4*)&A[grow * K1 + gk];
        else v = *(const float4*)&A2[grow * (K - K1) + gk - K1];
      } else if (MODE == 2) {
        int seg = gk >> 8;  // 256-aligned segments, float4 never straddles
        int src;
        if (seg == 0) src = grow;
        else src = nb[grow * 3 + 2] ? nb[grow * 3 + seg - 1] : -1;
        if (src >= 0) v = *(const float4*)&A[src * 256 + (gk & 255)];
      } else {  // MODE 3: virtual Hc, K=385
        if (gk + 3 < 256) v = *(const float4*)&A[grow * 256 + gk];
        else if (gk >= 256 && gk + 3 < 320) v = *(const float4*)&A2[gk - 256];
        else if (gk >= 320 && gk + 3 < 384) v = *(const float4*)&A3[grow * 64 + gk - 320];
        else {
          float tmp[4];
#pragma unroll
          for (int e = 0; e < 4; ++e) {
            int c = gk + e;
            float x = 0.f;
            if (c < 256) x = A[grow * 256 + c];
            else if (c < 320) x = A2[c - 256];
            else if (c < 384) x = A3[grow * 64 + c - 320];
            else if (c == 384) x = (grow < 64) ? A4[grow] : 0.f;
            tmp[e] = x;
          }
          v = make_float4(tmp[0], tmp[1], tmp[2], tmp[3]);
        }
      }
      *(float4*)&As[r][c0] = v;
    }
    // ---- load B tile (64 k x 64 n) ----
#pragma unroll
    for (int j = 0; j < 4; ++j) {
      int idx = t + j * 256;
      int r = idx >> 4;
      int c0 = (idx & 15) * 4;
      int gk = k0 + r;
      float4 v = make_float4(0.f, 0.f, 0.f, 0.f);
      if (gk < K) v = *(const float4*)&B[(size_t)gk * Nn + colbase + c0];
      *(float4*)&Bs[r][c0] = v;
    }
    __syncthreads();
    // ---- 4x4 micro-tile compute ----
#pragma unroll 8
    for (int kk = 0; kk < 64; ++kk) {
      float a0 = As[ty * 4 + 0][kk];
      float a1 = As[ty * 4 + 1][kk];
      float a2 = As[ty * 4 + 2][kk];
      float a3 = As[ty * 4 + 3][kk];
      float4 b = *(const float4*)&Bs[kk][tx * 4];
      acc[0][0] += a0 * b.x; acc[0][1] += a0 * b.y; acc[0][2] += a0 * b.z; acc[0][3] += a0 * b.w;
      acc[1][0] += a1 * b.x; acc[1][1] += a1 * b.y; acc[1][2] += a1 * b.z; acc[1][3] += a1 * b.w;
      acc[2][0] += a2 * b.x; acc[2][1] += a2 * b.y; acc[2][2] += a2 * b.z; acc[2][3] += a2 * b.w;
      acc[3][0] += a3 * b.x; acc[3][1] += a3 * b.y; acc[3][2] += a3 * b.z; acc[3][3] += a3 * b.w;
    }
    __syncthreads();
  }
  // ---- epilogue ----
  int col = colbase + tx * 4;
  float b0 = bias ? bias[col + 0] : 0.f;
  float b1 = bias ? bias[col + 1] : 0.f;
  float b2 = bias ? bias[col + 2] : 0.f;
  float b3 = bias ? bias[col + 3] : 0.f;
#pragma unroll
  for (int i = 0; i < 4; ++i) {
    int row = rowbase + ty * 4 + i;
    float4 o;
    o.x = acc[i][0] + b0; o.y = acc[i][1] + b1; o.z = acc[i][2] + b2; o.w = acc[i][3] + b3;
    if (act) {
      o.x = fmaxf(o.x, 0.f); o.y = fmaxf(o.y, 0.f);
      o.z = fmaxf(o.z, 0.f); o.w = fmaxf(o.w, 0.f);
    }
    *(float4*)&C[(size_t)row * Nn + col] = o;
  }
}

template <int MODE>
__global__ __launch_bounds__(256) void gemm_k(
    const float* A, const float* A2, const float* A3, const float* A4,
    const int* nb, const float* B, const float* bias, float* C,
    int M, int K, int Nn, int act, int K1) {
  gemm_body<MODE>(A, A2, A3, A4, nb, B, bias, C, M, K, Nn, act, K1,
                  blockIdx.x, blockIdx.y);
}

struct Ptrs3 {
  const float* B0; const float* B1; const float* B2;
  float* C0; float* C1; float* C2;
};

// three M=512,K=256,Nn=256 GEMMs sharing A, batched over gridDim.z
__global__ __launch_bounds__(256) void gemm3_k(const float* A, Ptrs3 p, int K) {
  const float* B = blockIdx.z == 0 ? p.B0 : blockIdx.z == 1 ? p.B1 : p.B2;
  float* C = blockIdx.z == 0 ? p.C0 : blockIdx.z == 1 ? p.C1 : p.C2;
  gemm_body<0>(A, nullptr, nullptr, nullptr, nullptr, B, nullptr, C,
               512, K, 256, 0, 0, blockIdx.x, blockIdx.y);
}

// ---------------- w[i] = dot(A[i,:], v)  (one wave per row) ----------------
__global__ void rowdot_kernel(const float* __restrict__ A, const float* __restrict__ v,
                              float* __restrict__ out, int K) {
  int i = blockIdx.x;
  int lane = threadIdx.x;
  float s = 0.f;
  for (int k = lane; k < K; k += 64) s += A[i * K + k] * v[k];
#pragma unroll
  for (int off = 32; off > 0; off >>= 1) s += __shfl_down(s, off, 64);
  if (lane == 0) out[i] = s;
}

// ---------------- H1: masked row softmax of w[j] over adj, then @Wh1 ------
__global__ void h1_kernel(const float* __restrict__ Wh1, const float* __restrict__ wsc,
                          const int* __restrict__ adj, float* __restrict__ H1) {
  __shared__ float el[NN];
  __shared__ float red[256];
  int i = blockIdx.x, tid = threadIdx.x;
  float m = -INFINITY;
  for (int j = tid; j < NN; j += 256) {
    float val = (adj[i * NN + j] != 0) ? wsc[j] : -INFINITY;
    el[j] = val;
    m = fmaxf(m, val);
  }
  red[tid] = m; __syncthreads();
  for (int s = 128; s > 0; s >>= 1) { if (tid < s) red[tid] = fmaxf(red[tid], red[tid + s]); __syncthreads(); }
  float mw = red[0];
  __syncthreads();
  float sum = 0.f;
  for (int j = tid; j < NN; j += 256) {
    float val = el[j];
    float e = (val == -INFINITY) ? 0.f : expf(val - mw);
    el[j] = e;
    sum += e;
  }
  red[tid] = sum; __syncthreads();
  for (int s = 128; s > 0; s >>= 1) { if (tid < s) red[tid] += red[tid + s]; __syncthreads(); }
  float inv = 1.f / red[0];
  __syncthreads();
  float acc = 0.f;
#pragma unroll 4
  for (int j = 0; j < NN; ++j) acc += el[j] * Wh1[j * 256 + tid];
  H1[i * 256 + tid] = acc * inv;
}

// ---------------- wc[k] = sum_h ce_w2[k,h]*(a_c0[h]+a_c1[h]) ----------------
__global__ void wc_kernel(const float* __restrict__ ce_w2, const float* __restrict__ a_c0,
                          const float* __restrict__ a_c1, float* __restrict__ wc) {
  __shared__ float acl[HD];
  int tid = threadIdx.x;
  if (tid < HD) acl[tid] = a_c0[tid] + a_c1[tid];
  __syncthreads();
  float s = 0.f;
#pragma unroll 8
  for (int h = 0; h < HD; ++h) s += ce_w2[tid * HD + h] * acl[h];
  wc[tid] = s;
}

// ---------------- pair kernel: per-block online softmax partials ----------
__global__ __launch_bounds__(256) void pair_kernel(
    const float* __restrict__ P, const float* __restrict__ Q,
    const float* __restrict__ b1, const float* __restrict__ wc,
    float* __restrict__ mpart, float* __restrict__ dpart, float* __restrict__ rpart) {
  __shared__ float Pl[16 * 257];
  __shared__ float Ql[16 * 257];
  __shared__ float bw[256];
  __shared__ float wcl[256];
  __shared__ float el[256];
  __shared__ float red[256];
  int tid = threadIdx.x;
  int i0 = blockIdx.y * 16, j0 = blockIdx.x * 16;
  for (int e = tid; e < 4096; e += 256) {
    int r = e >> 8, c = e & 255;
    Pl[r * 257 + c] = P[(i0 + r) * 256 + c];
    Ql[r * 257 + c] = Q[(j0 + r) * 256 + c];
  }
  bw[tid] = b1[tid];
  wcl[tid] = wc[tid];
  __syncthreads();
  int ti = tid >> 4, tj = tid & 15;
  const float* pr = &Pl[ti * 257];
  const float* qr = &Ql[tj * 257];
  float acc = 0.f;
#pragma unroll 4
  for (int k = 0; k < 256; ++k) {
    float v = pr[k] + qr[k] + bw[k];
    acc += fmaxf(v, 0.f) * wcl[k];
  }
  if (i0 + ti == j0 + tj) acc = -INFINITY;  // diagonal mask
  red[tid] = acc; __syncthreads();
  for (int s = 128; s > 0; s >>= 1) { if (tid < s) red[tid] = fmaxf(red[tid], red[tid + s]); __syncthreads(); }
  float mb = red[0];   // finite: at most 16 of 256 entries are -inf
  __syncthreads();
  float e = expf(acc - mb);  // -inf -> 0
  el[tid] = e;
  red[tid] = e; __syncthreads();
  for (int s = 128; s > 0; s >>= 1) { if (tid < s) red[tid] += red[tid + s]; __syncthreads(); }
  float db = red[0];
  float bk = bw[tid];
  float rk = 0.f;
  for (int p = 0; p < 256; ++p) {
    float ep = el[p];
    int ip = p >> 4, jp = p & 15;
    float v = Pl[ip * 257 + tid] + Ql[jp * 257 + tid] + bk;
    rk += ep * fmaxf(v, 0.f);
  }
  int b = blockIdx.y * 32 + blockIdx.x;
  rpart[b * 256 + tid] = rk;
  if (tid == 0) { mpart[b] = mb; dpart[b] = db; }
}

// blocks 0..255 reduce rvec[k]; block 256 reduces D. Global max inlined.
__global__ void combine_kernel(const float* __restrict__ mpart, const float* __restrict__ dpart,
                               const float* __restrict__ rpart,
                               float* __restrict__ rvec, float* __restrict__ Dval) {
  __shared__ float red[256];
  __shared__ float Msh;
  int tid = threadIdx.x;
  float m = -INFINITY;
  for (int b = tid; b < 1024; b += 256) m = fmaxf(m, mpart[b]);
  red[tid] = m; __syncthreads();
  for (int s = 128; s > 0; s >>= 1) { if (tid < s) red[tid] = fmaxf(red[tid], red[tid + s]); __syncthreads(); }
  if (tid == 0) Msh = red[0];
  __syncthreads();
  float M = Msh;
  int k = blockIdx.x;
  float s = 0.f;
  if (k < 256) {
    for (int b = tid; b < 1024; b += 256) s += expf(mpart[b] - M) * rpart[b * 256 + k];
  } else {
    for (int b = tid; b < 1024; b += 256) s += expf(mpart[b] - M) * dpart[b];
  }
  red[tid] = s; __syncthreads();
  for (int t2 = 128; t2 > 0; t2 >>= 1) { if (tid < t2) red[tid] += red[tid + t2]; __syncthreads(); }
  if (tid == 0) { if (k < 256) rvec[k] = red[0]; else Dval[0] = red[0]; }
}

__global__ void h2row_kernel(const float* __restrict__ rvec, const float* __restrict__ Dval,
                             const float* __restrict__ ce_w2, const float* __restrict__ ce_b2,
                             float* __restrict__ H2row) {
  int h = threadIdx.x;  // 64
  float invD = 1.f / Dval[0];
  float s = 0.f;
  for (int k = 0; k < 256; ++k) s += rvec[k] * ce_w2[k * HD + h];
  H2row[h] = s * invD + ce_b2[h];
}

// ---------------- H3: parallel prefix mean of tf rows ----------------
// tsb[i,j] = ts[i] broadcast => causal softmax is uniform: H3[i] = mean(tf[0..i]).
__global__ __launch_bounds__(1024) void h3scan_kernel(const float* __restrict__ tf,
                                                      float* __restrict__ H3) {
  __shared__ float segsum[16][65];
  int t = threadIdx.x;
  int h = t & 63, g = t >> 6;  // 16 segments x 32 rows
  float vals[32];
  float run = 0.f;
#pragma unroll
  for (int r = 0; r < 32; ++r) {
    run += tf[(g * 32 + r) * 64 + h];
    vals[r] = run;
  }
  segsum[g][h] = run;
  __syncthreads();
  float off = 0.f;
  for (int gg = 0; gg < g; ++gg) off += segsum[gg][h];
#pragma unroll
  for (int r = 0; r < 32; ++r) {
    int i = g * 32 + r;
    H3[i * 64 + h] = (vals[r] + off) / (float)(i + 1);
  }
}

// ---------------- first two neighbors per row ----------------
__global__ void nbr_kernel(const int* __restrict__ adj, int* __restrict__ nb) {
  int i = blockIdx.x;
  int lane = threadIdx.x;  // 64
  int n0 = -1, n1 = -1, cnt = 0;
  for (int c = 0; c < 8; ++c) {
    int j = c * 64 + lane;
    unsigned long long m = __ballot(adj[i * NN + j] != 0);
    cnt += (int)__popcll(m);
    if (n0 < 0 && m) { n0 = c * 64 + __builtin_ctzll(m); m &= (m - 1); }
    if (n1 < 0 && m) { n1 = c * 64 + __builtin_ctzll(m); }
  }
  if (lane == 0) {
    nb[i * 3] = n0;
    nb[i * 3 + 1] = n1;
    nb[i * 3 + 2] = (cnt >= 2) ? 1 : 0;
  }
}

// ---------------- column sums of cf4 (512x64) ----------------
__global__ void colsum_kernel(const float* __restrict__ cf4, float* __restrict__ h4vec) {
  __shared__ float part[8][65];
  int t = threadIdx.x;  // 512
  int h = t & 63, g = t >> 6;  // 8 groups x 64 rows
  float s = 0.f;
  for (int r = 0; r < 64; ++r) s += cf4[(g * 64 + r) * 64 + h];
  part[g][h] = s;
  __syncthreads();
  if (g == 0) {
    float tot = s;
    for (int gg = 1; gg < 8; ++gg) tot += part[gg][h];
    h4vec[h] = tot;
  }
}

// ---------------- layernorm + elu ----------------
__global__ void ln_elu_kernel(const float* __restrict__ X, const float* __restrict__ g,
                              const float* __restrict__ b, float* __restrict__ out) {
  __shared__ float red[256];
  int i = blockIdx.x, tid = threadIdx.x;
  float x = X[i * 256 + tid];
  red[tid] = x; __syncthreads();
  for (int s = 128; s > 0; s >>= 1) { if (tid < s) red[tid] += red[tid + s]; __syncthreads(); }
  float mu = red[0] * (1.f / 256.f);
  __syncthreads();
  float d = x - mu;
  red[tid] = d * d; __syncthreads();
  for (int s = 128; s > 0; s >>= 1) { if (tid < s) red[tid] += red[tid + s]; __syncthreads(); }
  float var = red[0] * (1.f / 256.f);
  float y = d / sqrtf(var + EPSV) * g[tid] + b[tid];
  out[i * 256 + tid] = (y > 0.f) ? y : (expf(y) - 1.f);
}

extern "C" void kernel_launch(void* const* d_in, const int* in_sizes, int n_in,
                              void* d_out, int out_size, void* d_ws, size_t ws_size,
                              hipStream_t stream) {
  const float* V      = (const float*)d_in[0];
  const int*   adj    = (const int*)  d_in[1];
  const float* ph     = (const float*)d_in[2];
  const float* W1     = (const float*)d_in[3];
  // d_in[4] = a_std0: cancels in row softmax of s1 — unused
  const float* a_std1 = (const float*)d_in[5];
  const float* ce_w1  = (const float*)d_in[6];
  const float* ce_b1  = (const float*)d_in[7];
  const float* ce_w2  = (const float*)d_in[8];
  const float* ce_b2  = (const float*)d_in[9];
  const float* a_c0   = (const float*)d_in[10];
  const float* a_c1   = (const float*)d_in[11];
  const float* te_w1  = (const float*)d_in[12];
  const float* te_b1  = (const float*)d_in[13];
  const float* te_w2  = (const float*)d_in[14];
  const float* te_b2  = (const float*)d_in[15];
  // d_in[16], d_in[17] = a_t0, a_t1: dead (uniform causal softmax) — unused
  const float* co_w1  = (const float*)d_in[18];
  const float* co_b1  = (const float*)d_in[19];
  const float* co_w2  = (const float*)d_in[20];
  const float* co_b2  = (const float*)d_in[21];
  // d_in[22], d_in[23] = a_co0, a_co1: softmax over size-1 axis == 1 — unused
  const float* W2     = (const float*)d_in[24];
  const float* Wo     = (const float*)d_in[25];
  const float* bo     = (const float*)d_in[26];
  const float* ln_g   = (const float*)d_in[27];
  const float* ln_b   = (const float*)d_in[28];
  float* out = (float*)d_out;

  float* ws = (float*)d_ws;
  size_t off = 0;
  auto alloc = [&](size_t n) { float* p = ws + off; off += (n + 15) & ~(size_t)15; return p; };

  // region A: phase 1 = Wh1|Pb|Qb ; phase 3 = T1|T2
  float* regA  = alloc(512 * 768);
  float* Wh1   = regA;
  float* Pb    = regA + 131072;
  float* Qb    = regA + 262144;
  float* T1    = regA;
  float* T2    = regA + 131072;
  float* wsc   = alloc(512);
  float* rpart = alloc(1024 * 256);
  float* wc    = alloc(256);
  float* mpart = alloc(1024);
  float* dpart = alloc(1024);
  float* rvec  = alloc(256);
  float* Dval  = alloc(1);
  float* H2row = alloc(64);
  float* tfh   = alloc(512 * 256);   // then cf4h
  float* cf4h  = tfh;
  float* tf    = alloc(512 * 64);
  float* H3    = alloc(512 * 64);
  int*   nb    = (int*)alloc(512 * 3);
  float* cf4   = alloc(512 * 64);
  float* h4vec = alloc(64);
  float* H1    = alloc(512 * 256);
  (void)ws_size; (void)in_sizes; (void)n_in; (void)out_size;

  dim3 tb(16, 16);

  // --- H1 + H2-P/Q in one batched launch ---
  Ptrs3 p3{W1, ce_w1, ce_w1 + 256 * 256, Wh1, Pb, Qb};
  gemm3_k<<<dim3(4, 8, 3), tb, 0, stream>>>(V, p3, 256);
  rowdot_kernel<<<512, 64, 0, stream>>>(Wh1, a_std1, wsc, 256);
  h1_kernel<<<512, 256, 0, stream>>>(Wh1, wsc, adj, H1);

  // --- H2 branch (pair MLP, algebraically reduced) ---
  wc_kernel<<<1, 256, 0, stream>>>(ce_w2, a_c0, a_c1, wc);
  pair_kernel<<<dim3(32, 32), 256, 0, stream>>>(Pb, Qb, ce_b1, wc, mpart, dpart, rpart);
  combine_kernel<<<257, 256, 0, stream>>>(mpart, dpart, rpart, rvec, Dval);
  h2row_kernel<<<1, 64, 0, stream>>>(rvec, Dval, ce_w2, ce_b2, H2row);

  // --- H3 branch (concat folded into A-loader, mode 1) ---
  gemm_k<1><<<dim3(4, 8), tb, 0, stream>>>(V, ph, nullptr, nullptr, nullptr,
                                           te_w1, te_b1, tfh, 512, 512, 256, 1, 256);
  gemm_k<0><<<dim3(1, 8), tb, 0, stream>>>(tfh, nullptr, nullptr, nullptr, nullptr,
                                           te_w2, te_b2, tf, 512, 256, 64, 0, 0);
  h3scan_kernel<<<1, 1024, 0, stream>>>(tf, H3);

  // --- H4 branch (gather folded into A-loader, mode 2) ---
  nbr_kernel<<<512, 64, 0, stream>>>(adj, nb);
  gemm_k<2><<<dim3(4, 8), tb, 0, stream>>>(V, nullptr, nullptr, nullptr, nb,
                                           co_w1, co_b1, cf4h, 512, 768, 256, 1, 0);
  gemm_k<0><<<dim3(1, 8), tb, 0, stream>>>(cf4h, nullptr, nullptr, nullptr, nullptr,
                                           co_w2, co_b2, cf4, 512, 256, 64, 0, 0);
  colsum_kernel<<<1, 512, 0, stream>>>(cf4, h4vec);

  // --- combine + output head (Hc virtualized into A-loader, mode 3) ---
  gemm_k<3><<<dim3(4, 8), tb, 0, stream>>>(H1, H2row, H3, h4vec, nullptr,
                                           W2, nullptr, T1, 512, 385, 256, 0, 0);
  gemm_k<0><<<dim3(4, 8), tb, 0, stream>>>(T1, nullptr, nullptr, nullptr, nullptr,
                                           Wo, bo, T2, 512, 256, 256, 0, 0);
  ln_elu_kernel<<<512, 256, 0, stream>>>(T2, ln_g, ln_b, out);
}